// Round 12
// baseline (58.818 us; speedup 1.0000x reference)
//
#include <hip/hip_runtime.h>
#include <hip/hip_bf16.h>
#include <math.h>

// QConv2d: new_rho = kron(Ux,Uy) @ rho @ kron(Ux,Uy)^T
// Per 64x64 tile T: O = W T W^T, W = Ufx (x) Ufy (64x64, shared, bf16).
// r12: SOFTWARE-PIPELINED version of r11 (same per-wave MFMA math, verbatim):
//  - grid 256 x 256thr (4 waves); each block runs 4 units (64 rows x 256
//    cols) with double-buffered LDS staging:
//      loads(u+1) issued BEFORE compute(u); LDS-write(u+1) after; 1 barrier/unit.
//    -> reads, writes and MFMA overlap continuously (fill-like streaming),
//    killing the read-burst/compute/write-burst convoy that pinned r2-r11
//    at ~41us with every pipe idle.
//  - stage loads: 64B-aligned float4 per instr (4 rows x 4 full sectors).
//  - LDS layout/swizzle and GEMM fragment addressing = r11 (passed, 0.031).

typedef __attribute__((ext_vector_type(8))) short short8_t;  // 8 bf16
typedef __attribute__((ext_vector_type(4))) float f32x4;

__global__ void setup_w(const float* __restrict__ phi_x,
                        const float* __restrict__ phi_y,
                        unsigned short* __restrict__ W) {
    __shared__ float U[2][64];
    const int t = threadIdx.x;
    if (t < 2) {
        const float* phi = (t == 0) ? phi_x : phi_y;
        float Um[8][8];
#pragma unroll
        for (int i = 0; i < 8; ++i)
#pragma unroll
            for (int j = 0; j < 8; ++j) Um[i][j] = (i == j) ? 1.0f : 0.0f;
        int idx = 0;
#pragma unroll
        for (int i = 1; i < 8; ++i) {
#pragma unroll
            for (int j = i; j >= 1; --j) {
                const float c = cosf(phi[idx]);
                const float s = sinf(phi[idx]);
#pragma unroll
                for (int m = 0; m < 8; ++m) {
                    const float a = Um[j - 1][m], b = Um[j][m];
                    Um[j - 1][m] = c * a + s * b;
                    Um[j][m]     = -s * a + c * b;
                }
                ++idx;
            }
        }
#pragma unroll
        for (int i = 0; i < 8; ++i)
#pragma unroll
            for (int j = 0; j < 8; ++j) U[t][i * 8 + j] = Um[i][j];
    }
    __syncthreads();
    const int xi = t >> 3, yi = t & 7;
#pragma unroll
    for (int j = 0; j < 64; ++j) {
        const int xj = j >> 3, yj = j & 7;
        const float w = U[0][xi * 8 + xj] * U[1][yi * 8 + yj];
        __hip_bfloat16 h = __float2bfloat16(w);
        W[t * 64 + j] = *reinterpret_cast<const unsigned short*>(&h);
    }
}

__device__ __forceinline__ unsigned short bf16bits(float v) {
    __hip_bfloat16 h = __float2bfloat16(v);
    return *reinterpret_cast<const unsigned short*>(&h);
}

// unit decode: uid = bid*4 + U -> (b, bi, ch2)
#define STAGE_LOAD(U)                                                          \
    do {                                                                       \
        const int uid_ = blockIdx.x * 4 + (U);                                 \
        const int ch2_ = uid_ & 3, bi_ = (uid_ >> 2) & 15, bb_ = uid_ >> 6;    \
        const float* __restrict__ sp_ =                                        \
            rho + ((size_t)bb_ << 20) +                                        \
            (size_t)((bi_ >> 2) * 256 + (bi_ & 3) * 8 + grow_off) * 1024 +     \
            ch2_ * 256 + lq * 4;                                               \
        _Pragma("unroll")                                                      \
        for (int j = 0; j < 16; ++j)                                           \
            v[j] = *reinterpret_cast<const float4*>(sp_ + j * 16);             \
    } while (0)

#define STAGE_WRITE(BUF)                                                       \
    do {                                                                       \
        _Pragma("unroll")                                                      \
        for (int j = 0; j < 16; ++j) {                                         \
            const int chunk_ = (((lq >> 1) * 8) + ((j >> 1) & 7)) ^ r15;       \
            ushort4 h_;                                                        \
            h_.x = bf16bits(v[j].x); h_.y = bf16bits(v[j].y);                  \
            h_.z = bf16bits(v[j].z); h_.w = bf16bits(v[j].w);                  \
            *reinterpret_cast<ushort4*>(                                       \
                &L[(((BUF) * 2 + (j & 1)) * 64 + rr) * 128 + (chunk_ << 3) +   \
                   (lq & 1) * 4]) = h_;                                        \
        }                                                                      \
    } while (0)

#define COMPUTE(U, BUF)                                                        \
    do {                                                                       \
        const int uid_ = blockIdx.x * 4 + (U);                                 \
        const int ch2_ = uid_ & 3, bi_ = (uid_ >> 2) & 15, bb_ = uid_ >> 6;    \
        const size_t B0_ = (size_t)bb_ << 20;                                  \
        const int rowb_ = (bi_ >> 2) * 256 + (bi_ & 3) * 8;                    \
        const unsigned short* __restrict__ Tp_ =                               \
            &L[((BUF) * 2 + (w >> 1)) * 8192];                                 \
        unsigned short* __restrict__ Qs_ = &L[32768 + w * 1024];               \
        const int wc_ = (w & 1) * 8;                                           \
        const int bx2_ = ch2_, by2_ = w;                                       \
        _Pragma("unroll")                                                      \
        for (int m = 0; m < 4; ++m) {                                          \
            const short8_t AW0 = *reinterpret_cast<const short8_t*>(           \
                Wg + (16 * m + ln) * 64 + q * 8);                              \
            const short8_t AW1 = *reinterpret_cast<const short8_t*>(           \
                Wg + (16 * m + ln) * 64 + 32 + q * 8);                         \
            f32x4 acc[4];                                                      \
            _Pragma("unroll")                                                  \
            for (int tc = 0; tc < 4; ++tc) {                                   \
                const int prow = 16 * tc + ln;                                 \
                const short8_t BT0 = *reinterpret_cast<const short8_t*>(       \
                    Tp_ + prow * 128 + (((wc_ + 0 + q) ^ (prow & 15)) << 3));  \
                const short8_t BT1 = *reinterpret_cast<const short8_t*>(       \
                    Tp_ + prow * 128 + (((wc_ + 4 + q) ^ (prow & 15)) << 3));  \
                f32x4 c = {0.0f, 0.0f, 0.0f, 0.0f};                            \
                c = __builtin_amdgcn_mfma_f32_16x16x32_bf16(AW0, BT0, c, 0, 0, 0); \
                c = __builtin_amdgcn_mfma_f32_16x16x32_bf16(AW1, BT1, c, 0, 0, 0); \
                acc[tc] = c;                                                   \
            }                                                                  \
            _Pragma("unroll")                                                  \
            for (int tc = 0; tc < 4; ++tc)                                     \
                _Pragma("unroll")                                              \
                for (int i = 0; i < 4; ++i) {                                  \
                    const int qrow = 4 * q + i;                                \
                    const int qcol = 16 * tc + ln;                             \
                    Qs_[qrow * 64 + (((qcol >> 3) ^ (qrow & 7)) << 3) +        \
                        (qcol & 7)] = bf16bits(acc[tc][i]);                    \
                }                                                              \
            const short8_t AQ0 = *reinterpret_cast<const short8_t*>(           \
                Qs_ + ln * 64 + (((0 + q) ^ (ln & 7)) << 3));                  \
            const short8_t AQ1 = *reinterpret_cast<const short8_t*>(           \
                Qs_ + ln * 64 + (((4 + q) ^ (ln & 7)) << 3));                  \
            _Pragma("unroll")                                                  \
            for (int tc = 0; tc < 4; ++tc) {                                   \
                const short8_t BW0 = *reinterpret_cast<const short8_t*>(       \
                    Wg + (16 * tc + ln) * 64 + q * 8);                         \
                const short8_t BW1 = *reinterpret_cast<const short8_t*>(       \
                    Wg + (16 * tc + ln) * 64 + 32 + q * 8);                    \
                f32x4 o = {0.0f, 0.0f, 0.0f, 0.0f};                            \
                o = __builtin_amdgcn_mfma_f32_16x16x32_bf16(AQ0, BW0, o, 0, 0, 0); \
                o = __builtin_amdgcn_mfma_f32_16x16x32_bf16(AQ1, BW1, o, 0, 0, 0); \
                const int growg = rowb_ + (2 * tc + (ln >> 3)) * 32 + (ln & 7);\
                const int c0    = 16 * m + 4 * q;                              \
                const int gcol  = bx2_ * 256 + (c0 >> 3) * 32 + by2_ * 8 +     \
                                 (c0 & 7);                                     \
                *reinterpret_cast<float4*>(out + B0_ + (size_t)growg * 1024 +  \
                                           gcol) =                             \
                    make_float4(o[0], o[1], o[2], o[3]);                       \
            }                                                                  \
        }                                                                      \
    } while (0)

__global__ __launch_bounds__(256) void qconv_pipe(const float* __restrict__ rho,
                                                  const unsigned short* __restrict__ Wg,
                                                  float* __restrict__ out) {
    extern __shared__ __align__(16) unsigned short L[];  // 40960 shorts = 80KB
    // [0,32768): 2 bufs x 2 pairs x [64 rows][128 cols] bf16 (chunk-swizzled)
    // [32768,40960): 4 x 1024 Q-strips
    const int t = threadIdx.x;
    const int w = t >> 6;
    const int l = t & 63;

    // staging geometry: lane covers row rr, 16B piece lq; instr j walks 64B
    const int lq = l & 3;
    const int rr = w * 16 + (l >> 2);
    const int r15 = rr & 15;
    const int grow_off = (rr >> 3) * 32 + (rr & 7);

    // fragment geometry
    const int ln = l & 15;
    const int q  = l >> 4;

    float4 v[16];

    // prologue
    STAGE_LOAD(0);
    STAGE_WRITE(0);
    __syncthreads();

    // pipelined units
    STAGE_LOAD(1);
    COMPUTE(0, 0);
    STAGE_WRITE(1);
    __syncthreads();

    STAGE_LOAD(2);
    COMPUTE(1, 1);
    STAGE_WRITE(0);
    __syncthreads();

    STAGE_LOAD(3);
    COMPUTE(2, 0);
    STAGE_WRITE(1);
    __syncthreads();

    COMPUTE(3, 1);
}

extern "C" void kernel_launch(void* const* d_in, const int* in_sizes, int n_in,
                              void* d_out, int out_size, void* d_ws, size_t ws_size,
                              hipStream_t stream) {
    const float* rho   = (const float*)d_in[0];
    const float* phi_x = (const float*)d_in[1];
    const float* phi_y = (const float*)d_in[2];
    float* out = (float*)d_out;
    unsigned short* W = (unsigned short*)d_ws;

    setup_w<<<1, 64, 0, stream>>>(phi_x, phi_y, W);
    qconv_pipe<<<256, 256, 81920, stream>>>(rho, W, out);
}

// Round 13
// 47.627 us; speedup vs baseline: 1.2350x; 1.2350x over previous
//
#include <hip/hip_runtime.h>
#include <hip/hip_bf16.h>
#include <math.h>

// QConv2d: new_rho = kron(Ux,Uy) @ rho @ kron(Ux,Uy)^T
// Per 64x64 tile T: O = W T W^T, W = Ufx (x) Ufy (64x64, shared, bf16).
//
// r13 = r12's verified 4-wave COMPUTE + r11's contiguous IO + 4 blocks/CU +
// forced load-MLP:
//  - grid 1024 x 256thr; block = (b, bi, ch2) = 64 rows x 256 contiguous cols.
//  - staging: instr j = one FULL 1KB-contiguous global row; all 16 loads
//    issued before any convert via sched_barrier(0) -> 16 loads in flight
//    per wave (fixes r11's VGPR=44 / ~3-deep read chain).
//  - LDS: 2 pair-tiles [64][128] bf16 chunk-swizzled + 4 Q-strips = 40KB
//    -> 4 blocks/CU (16 waves/CU), barrier convoys staggered across blocks.
//  - COMPUTE/stores: verbatim r12 (passed, absmax 0.031): per wave one
//    64x64 tile, GEMM1 Q=W@T^T, Q->bf16 strip, GEMM2 O^T=Q@W^T, float4
//    stores (full sectors).

typedef __attribute__((ext_vector_type(8))) short short8_t;  // 8 bf16
typedef __attribute__((ext_vector_type(4))) float f32x4;

__global__ void setup_w(const float* __restrict__ phi_x,
                        const float* __restrict__ phi_y,
                        unsigned short* __restrict__ W) {
    __shared__ float U[2][64];
    const int t = threadIdx.x;
    if (t < 2) {
        const float* phi = (t == 0) ? phi_x : phi_y;
        float Um[8][8];
#pragma unroll
        for (int i = 0; i < 8; ++i)
#pragma unroll
            for (int j = 0; j < 8; ++j) Um[i][j] = (i == j) ? 1.0f : 0.0f;
        int idx = 0;
#pragma unroll
        for (int i = 1; i < 8; ++i) {
#pragma unroll
            for (int j = i; j >= 1; --j) {
                const float c = cosf(phi[idx]);
                const float s = sinf(phi[idx]);
#pragma unroll
                for (int m = 0; m < 8; ++m) {
                    const float a = Um[j - 1][m], b = Um[j][m];
                    Um[j - 1][m] = c * a + s * b;
                    Um[j][m]     = -s * a + c * b;
                }
                ++idx;
            }
        }
#pragma unroll
        for (int i = 0; i < 8; ++i)
#pragma unroll
            for (int j = 0; j < 8; ++j) U[t][i * 8 + j] = Um[i][j];
    }
    __syncthreads();
    const int xi = t >> 3, yi = t & 7;
#pragma unroll
    for (int j = 0; j < 64; ++j) {
        const int xj = j >> 3, yj = j & 7;
        const float w = U[0][xi * 8 + xj] * U[1][yi * 8 + yj];
        __hip_bfloat16 h = __float2bfloat16(w);
        W[t * 64 + j] = *reinterpret_cast<const unsigned short*>(&h);
    }
}

__device__ __forceinline__ unsigned short bf16bits(float v) {
    __hip_bfloat16 h = __float2bfloat16(v);
    return *reinterpret_cast<const unsigned short*>(&h);
}

__global__ __launch_bounds__(256) void qconv_mfma3(const float* __restrict__ rho,
                                                   const unsigned short* __restrict__ Wg,
                                                   float* __restrict__ out) {
    extern __shared__ __align__(16) unsigned short L[];  // 20480 shorts = 40KB
    // [0,16384): 2 pair-tiles x [64 rows][128 cols] bf16, chunk-swizzled
    // [16384,20480): 4 x 1024-short Q-strips
    const int t = threadIdx.x;
    const int w = t >> 6;   // wave 0..3
    const int l = t & 63;

    const int uid = blockIdx.x;
    const int ch2 = uid & 3;          // 256-col chunk
    const int bi  = (uid >> 2) & 15;  // row block (bx1*4+by1)
    const int b   = uid >> 6;

    const size_t B0   = (size_t)b << 20;
    const int    rowb = (bi >> 2) * 256 + (bi & 3) * 8;

    // ---------------- stage: 16 full-row 1KB-contiguous loads ----------------
    const float* __restrict__ src = rho + B0 + ch2 * 256 + 4 * l;
    float4 v[16];
#pragma unroll
    for (int j = 0; j < 16; ++j) {
        const int rt   = j * 4 + w;                       // T-row
        const int grow = rowb + (rt >> 3) * 32 + (rt & 7);
        v[j] = *reinterpret_cast<const float4*>(src + (size_t)grow * 1024);
    }
    __builtin_amdgcn_sched_barrier(0);  // all 16 loads in flight before use

    {
        const int u0 = (l >> 2) & 1;                       // pair-tile
        const int pc = ((l >> 1) & 1) * 8 + ((l >> 3) & 7);  // chunk pre-swizzle
        const int el = (l & 1) * 4;                        // elem within chunk
#pragma unroll
        for (int j = 0; j < 16; ++j) {
            const int rt = j * 4 + w;
            ushort4 h;
            h.x = bf16bits(v[j].x); h.y = bf16bits(v[j].y);
            h.z = bf16bits(v[j].z); h.w = bf16bits(v[j].w);
            *reinterpret_cast<ushort4*>(
                &L[(u0 * 64 + rt) * 128 + ((pc ^ (rt & 15)) << 3) + el]) = h;
        }
    }
    __syncthreads();

    // ---------------- compute: wave w = tile (bx2=ch2, by2=w) ----------------
    const int ln = l & 15;
    const int q  = l >> 4;
    const unsigned short* __restrict__ Tp = &L[(w >> 1) * 8192];
    unsigned short* __restrict__ Qs       = &L[16384 + w * 1024];
    const int wc  = (w & 1) * 8;
    const int bx2 = ch2, by2 = w;

#pragma unroll
    for (int m = 0; m < 4; ++m) {
        // GEMM1: Q16 = W[16m..16m+16) @ T^T
        const short8_t AW0 = *reinterpret_cast<const short8_t*>(
            Wg + (16 * m + ln) * 64 + q * 8);
        const short8_t AW1 = *reinterpret_cast<const short8_t*>(
            Wg + (16 * m + ln) * 64 + 32 + q * 8);
        f32x4 acc[4];
#pragma unroll
        for (int tc = 0; tc < 4; ++tc) {
            const int prow = 16 * tc + ln;
            const short8_t BT0 = *reinterpret_cast<const short8_t*>(
                Tp + prow * 128 + (((wc + 0 + q) ^ (prow & 15)) << 3));
            const short8_t BT1 = *reinterpret_cast<const short8_t*>(
                Tp + prow * 128 + (((wc + 4 + q) ^ (prow & 15)) << 3));
            f32x4 c = {0.0f, 0.0f, 0.0f, 0.0f};
            c = __builtin_amdgcn_mfma_f32_16x16x32_bf16(AW0, BT0, c, 0, 0, 0);
            c = __builtin_amdgcn_mfma_f32_16x16x32_bf16(AW1, BT1, c, 0, 0, 0);
            acc[tc] = c;
        }

        // Q16 -> bf16 LDS strip (wave-private)
#pragma unroll
        for (int tc = 0; tc < 4; ++tc)
#pragma unroll
            for (int i = 0; i < 4; ++i) {
                const int qrow = 4 * q + i;
                const int qcol = 16 * tc + ln;
                Qs[qrow * 64 + (((qcol >> 3) ^ (qrow & 7)) << 3) + (qcol & 7)] =
                    bf16bits(acc[tc][i]);
            }

        // GEMM2: O16^T = Q16 @ W^T ; direct full-sector float4 stores
        const short8_t AQ0 = *reinterpret_cast<const short8_t*>(
            Qs + ln * 64 + (((0 + q) ^ (ln & 7)) << 3));
        const short8_t AQ1 = *reinterpret_cast<const short8_t*>(
            Qs + ln * 64 + (((4 + q) ^ (ln & 7)) << 3));
#pragma unroll
        for (int tc = 0; tc < 4; ++tc) {
            const short8_t BW0 = *reinterpret_cast<const short8_t*>(
                Wg + (16 * tc + ln) * 64 + q * 8);
            const short8_t BW1 = *reinterpret_cast<const short8_t*>(
                Wg + (16 * tc + ln) * 64 + 32 + q * 8);
            f32x4 o = {0.0f, 0.0f, 0.0f, 0.0f};
            o = __builtin_amdgcn_mfma_f32_16x16x32_bf16(AQ0, BW0, o, 0, 0, 0);
            o = __builtin_amdgcn_mfma_f32_16x16x32_bf16(AQ1, BW1, o, 0, 0, 0);

            const int grow = rowb + (2 * tc + (ln >> 3)) * 32 + (ln & 7);
            const int c0   = 16 * m + 4 * q;
            const int gcol = bx2 * 256 + (c0 >> 3) * 32 + by2 * 8 + (c0 & 7);
            *reinterpret_cast<float4*>(out + B0 + (size_t)grow * 1024 + gcol) =
                make_float4(o[0], o[1], o[2], o[3]);
        }
    }
}

extern "C" void kernel_launch(void* const* d_in, const int* in_sizes, int n_in,
                              void* d_out, int out_size, void* d_ws, size_t ws_size,
                              hipStream_t stream) {
    const float* rho   = (const float*)d_in[0];
    const float* phi_x = (const float*)d_in[1];
    const float* phi_y = (const float*)d_in[2];
    float* out = (float*)d_out;
    unsigned short* W = (unsigned short*)d_ws;

    setup_w<<<1, 64, 0, stream>>>(phi_x, phi_y, W);
    qconv_mfma3<<<1024, 256, 40960, stream>>>(rho, W, out);
}